// Round 1
// baseline (5469.021 us; speedup 1.0000x reference)
//
#include <hip/hip_runtime.h>
#include <math.h>

// Problem constants (E,B,M,C) = (64, 512, 128, 128), sigma=0.5, eps=1e-6
#define MM   128
#define CC   128
#define EE   64
#define BB   512
#define LDA  132          // padded row stride for A in LDS (bank balance, 16B aligned)
#define SIG2 0.25f
#define EPSV 1e-6f

// dynamic LDS layout (floats)
#define A_OFF      0
#define V_OFF      (128*132)            // 11 vector slots of 128
#define WRED_OFF   (V_OFF + 11*128)     // 16 floats: [wave][slot]
#define SMEM_FLOATS (WRED_OFF + 16)
#define SMEM_BYTES  (SMEM_FLOATS * 4)   // 73,280 B -> 2 blocks/CU

#define VS(i) (V_OFF + (i)*128)

// ---------------------------------------------------------------------------
// Compute Ginv0 = (A A^T + SIG2*I)^-1 where A ([128][LDA]) is in LDS.
// Destroys the A buffer (used as scratch for Gauss-Jordan). Result in Greg
// (thread (r,h) holds row r, cols [64h,64h+64)). Caller must have synced
// after loading A. SPD -> no pivoting needed.
// ---------------------------------------------------------------------------
__device__ void compute_ginv(float* sm, float (&Greg)[64],
                             const int r, const int h, const int cb) {
    float* A = sm + A_OFF;
    #pragma unroll
    for (int j = 0; j < 64; ++j) Greg[j] = 0.f;
    // G0 = A A^T (row r dot rows cb..cb+63), float4 over C
    #pragma unroll 1
    for (int jt = 0; jt < 32; ++jt) {
        const float4 ar = *(const float4*)&A[r*LDA + 4*jt];
        #pragma unroll
        for (int k = 0; k < 64; ++k) {
            const float4 ac = *(const float4*)&A[(cb + k)*LDA + 4*jt];
            Greg[k] += ar.x*ac.x + ar.y*ac.y + ar.z*ac.z + ar.w*ac.w;
        }
    }
    #pragma unroll
    for (int j = 0; j < 64; ++j)
        if (cb + j == r) Greg[j] += SIG2;
    __syncthreads();                    // all G0 reads of A done
    // dump G0 over A
    #pragma unroll
    for (int jt = 0; jt < 16; ++jt) {
        float4 v; v.x = Greg[4*jt]; v.y = Greg[4*jt+1]; v.z = Greg[4*jt+2]; v.w = Greg[4*jt+3];
        *(float4*)&A[r*LDA + cb + 4*jt] = v;
    }
    // in-place Gauss-Jordan inversion
    #pragma unroll 1
    for (int k = 0; k < 128; ++k) {
        __syncthreads();
        if (r == k) {   // pivot row pair (same wave -> lockstep read-before-write)
            const float pinv = 1.0f / A[k*LDA + k];
            if (h == (k >> 6)) A[k*LDA + k] = 1.0f;
            #pragma unroll
            for (int jt = 0; jt < 16; ++jt) {
                float4 g = *(float4*)&A[k*LDA + cb + 4*jt];
                g.x *= pinv; g.y *= pinv; g.z *= pinv; g.w *= pinv;
                *(float4*)&A[k*LDA + cb + 4*jt] = g;
            }
        }
        __syncthreads();
        if (r != k) {
            const float f = A[r*LDA + k];
            #pragma unroll
            for (int jt = 0; jt < 16; ++jt) {
                float4 own = *(float4*)&A[r*LDA + cb + 4*jt];
                const float4 rk = *(const float4*)&A[k*LDA + cb + 4*jt];
                own.x -= f*rk.x; own.y -= f*rk.y; own.z -= f*rk.z; own.w -= f*rk.w;
                *(float4*)&A[r*LDA + cb + 4*jt] = own;
            }
            // blind subtract gave f - f*pinv at col k; desired -f*pinv
            if (k >= cb && k < cb + 64) A[r*LDA + k] -= f;
        }
    }
    __syncthreads();
    #pragma unroll
    for (int j = 0; j < 64; ++j) Greg[j] = A[r*LDA + cb + j];
    __syncthreads();                    // caller may now overwrite A
}

// setup: one block computes Ginv0 into d_ws (shared by all batches)
__global__ __launch_bounds__(256, 2) void gpm_setup(const float* __restrict__ mean0,
                                                    float* __restrict__ ginv0) {
    extern __shared__ float sm[];
    const int t = threadIdx.x, r = t >> 1, h = t & 1, cb = h << 6;
    float* A = sm + A_OFF;
    const float* src = mean0 + r*CC + cb;
    #pragma unroll
    for (int jt = 0; jt < 16; ++jt)
        *(float4*)&A[r*LDA + cb + 4*jt] = *(const float4*)&src[4*jt];
    __syncthreads();
    float Greg[64];
    compute_ginv(sm, Greg, r, h, cb);
    #pragma unroll
    for (int jt = 0; jt < 16; ++jt) {
        float4 v; v.x = Greg[4*jt]; v.y = Greg[4*jt+1]; v.z = Greg[4*jt+2]; v.w = Greg[4*jt+3];
        *(float4*)&ginv0[r*CC + cb + 4*jt] = v;
    }
}

#define DOT_ACC(p, slot) do { float _p = (p);                 \
    _p += __shfl_xor(_p, 1, 64);  _p += __shfl_xor(_p, 2, 64); \
    _p += __shfl_xor(_p, 4, 64);  _p += __shfl_xor(_p, 8, 64); \
    _p += __shfl_xor(_p, 16, 64); _p += __shfl_xor(_p, 32, 64);\
    if (lane == 0) wred[wv*4 + (slot)] = _p; } while (0)

// ---------------------------------------------------------------------------
// Main kernel: one block per batch element, 64 sequential Kalman steps.
// A (mean) in LDS; U (cov) and Ginv in registers (row r, cols [64h,64h+64)).
// ---------------------------------------------------------------------------
__global__ __launch_bounds__(256, 2) void gpm_main(
        const float* __restrict__ zin, const float* __restrict__ mean0,
        const float* __restrict__ lvar, float* __restrict__ out,
        const float* __restrict__ ginv0, const int use_ws) {
    extern __shared__ float sm[];
    float* A    = sm + A_OFF;
    float* vz   = sm + VS(0);
    float* vaz  = sm + VS(1);
    float* vw0  = sm + VS(2);
    float* vt0  = sm + VS(3);
    float* vrr  = sm + VS(4);
    float* vw   = sm + VS(5);
    float* vdl  = sm + VS(6);
    float* vv_  = sm + VS(7);
    float* vuw  = sm + VS(8);
    float* vg1  = sm + VS(9);
    float* vg2  = sm + VS(10);
    float* wred = sm + WRED_OFF;

    const int t = threadIdx.x;
    const int b = blockIdx.x;
    const int r = t >> 1;
    const int h = t & 1;
    const int cb = h << 6;
    const int wv = t >> 6;
    const int lane = t & 63;

    // prologue: A0 -> LDS
    {
        const float* src = mean0 + r*CC + cb;
        #pragma unroll
        for (int jt = 0; jt < 16; ++jt)
            *(float4*)&A[r*LDA + cb + 4*jt] = *(const float4*)&src[4*jt];
    }
    const float pvar = expf(lvar[0]) + EPSV;   // prior variance p
    float Ureg[64], Greg[64];
    #pragma unroll
    for (int j = 0; j < 64; ++j) Ureg[j] = (cb + j == r) ? pvar : 0.f;

    if (use_ws) {
        const float* src = ginv0 + r*CC + cb;
        #pragma unroll
        for (int jt = 0; jt < 16; ++jt) {
            const float4 v = *(const float4*)&src[4*jt];
            Greg[4*jt] = v.x; Greg[4*jt+1] = v.y; Greg[4*jt+2] = v.z; Greg[4*jt+3] = v.w;
        }
    } else {
        __syncthreads();
        compute_ginv(sm, Greg, r, h, cb);      // destroys A, internal syncs
        const float* src = mean0 + r*CC + cb;  // reload A0
        #pragma unroll
        for (int jt = 0; jt < 16; ++jt)
            *(float4*)&A[r*LDA + cb + 4*jt] = *(const float4*)&src[4*jt];
    }
    if (t < 32) {                               // z for e=0
        const float4 zz = *(const float4*)&zin[(size_t)b*CC + 4*t];
        *(float4*)&vz[4*t] = zz;
    }
    __syncthreads();

    #pragma unroll 1
    for (int e = 0; e < EE; ++e) {
        // P1: az = A z
        {
            float4 acc = {0,0,0,0};
            #pragma unroll
            for (int jt = 0; jt < 16; ++jt) {
                const float4 a = *(const float4*)&A[r*LDA + cb + 4*jt];
                const float4 x = *(const float4*)&vz[cb + 4*jt];
                acc.x += a.x*x.x; acc.y += a.y*x.y; acc.z += a.z*x.z; acc.w += a.w*x.w;
            }
            float s = (acc.x+acc.y)+(acc.z+acc.w); s += __shfl_xor(s, 1, 64);
            if (h == 0) vaz[r] = s;
        }
        __syncthreads();
        // P2: w0 = Ginv az
        {
            float4 acc = {0,0,0,0};
            #pragma unroll
            for (int jt = 0; jt < 16; ++jt) {
                const float4 x = *(const float4*)&vaz[cb + 4*jt];
                acc.x += Greg[4*jt]*x.x;   acc.y += Greg[4*jt+1]*x.y;
                acc.z += Greg[4*jt+2]*x.z; acc.w += Greg[4*jt+3]*x.w;
            }
            float s = (acc.x+acc.y)+(acc.z+acc.w); s += __shfl_xor(s, 1, 64);
            if (h == 0) vw0[r] = s;
        }
        __syncthreads();
        // P3: t0 = A^T w0   (output col index = r)
        {
            float acc = 0.f;
            #pragma unroll
            for (int mt = 0; mt < 16; ++mt) {
                const float4 x = *(const float4*)&vw0[cb + 4*mt];
                const float* ap = &A[(cb + 4*mt)*LDA + r];
                acc += x.x*ap[0] + x.y*ap[LDA] + x.z*ap[2*LDA] + x.w*ap[3*LDA];
            }
            acc += __shfl_xor(acc, 1, 64);
            if (h == 0) vt0[r] = acc;
        }
        __syncthreads();
        // P4: rr = az - A t0 - SIG2 w0   (= az - G w0, residual for refinement)
        {
            float4 acc = {0,0,0,0};
            #pragma unroll
            for (int jt = 0; jt < 16; ++jt) {
                const float4 a = *(const float4*)&A[r*LDA + cb + 4*jt];
                const float4 x = *(const float4*)&vt0[cb + 4*jt];
                acc.x += a.x*x.x; acc.y += a.y*x.y; acc.z += a.z*x.z; acc.w += a.w*x.w;
            }
            float s = (acc.x+acc.y)+(acc.z+acc.w); s += __shfl_xor(s, 1, 64);
            if (h == 0) vrr[r] = vaz[r] - s - SIG2*vw0[r];
        }
        __syncthreads();
        // P5: w = w0 + Ginv rr
        {
            float4 acc = {0,0,0,0};
            #pragma unroll
            for (int jt = 0; jt < 16; ++jt) {
                const float4 x = *(const float4*)&vrr[cb + 4*jt];
                acc.x += Greg[4*jt]*x.x;   acc.y += Greg[4*jt+1]*x.y;
                acc.z += Greg[4*jt+2]*x.z; acc.w += Greg[4*jt+3]*x.w;
            }
            float s = (acc.x+acc.y)+(acc.z+acc.w); s += __shfl_xor(s, 1, 64);
            if (h == 0) vw[r] = vw0[r] + s;
        }
        __syncthreads();
        // P6: t2 = A^T w -> dl = z - t2 (+d2); uw = U w (+sig)
        float d2, sig, inv_sig;
        {
            float acc = 0.f;
            #pragma unroll
            for (int mt = 0; mt < 16; ++mt) {
                const float4 x = *(const float4*)&vw[cb + 4*mt];
                const float* ap = &A[(cb + 4*mt)*LDA + r];
                acc += x.x*ap[0] + x.y*ap[LDA] + x.z*ap[2*LDA] + x.w*ap[3*LDA];
            }
            acc += __shfl_xor(acc, 1, 64);
            const float dval = vz[r] - acc;
            if (h == 0) vdl[r] = dval;
            float p0 = (h == 0) ? dval*dval : 0.f;
            DOT_ACC(p0, 0);
            float4 a2 = {0,0,0,0};
            #pragma unroll
            for (int jt = 0; jt < 16; ++jt) {
                const float4 x = *(const float4*)&vw[cb + 4*jt];
                a2.x += Ureg[4*jt]*x.x;   a2.y += Ureg[4*jt+1]*x.y;
                a2.z += Ureg[4*jt+2]*x.z; a2.w += Ureg[4*jt+3]*x.w;
            }
            float s2 = (a2.x+a2.y)+(a2.z+a2.w); s2 += __shfl_xor(s2, 1, 64);
            if (h == 0) vuw[r] = s2;
            float p1 = (h == 0) ? s2 * vw[r] : 0.f;
            DOT_ACC(p1, 1);
        }
        __syncthreads();
        d2  = wred[0] + wred[4] + wred[8]  + wred[12];
        sig = wred[1] + wred[5] + wred[9]  + wred[13] + SIG2;
        inv_sig = 1.0f / sig;
        // P7: vv = A dl  (exact A*delta, tracks gram of actual A)
        {
            float4 acc = {0,0,0,0};
            #pragma unroll
            for (int jt = 0; jt < 16; ++jt) {
                const float4 a = *(const float4*)&A[r*LDA + cb + 4*jt];
                const float4 x = *(const float4*)&vdl[cb + 4*jt];
                acc.x += a.x*x.x; acc.y += a.y*x.y; acc.z += a.z*x.z; acc.w += a.w*x.w;
            }
            float s = (acc.x+acc.y)+(acc.z+acc.w); s += __shfl_xor(s, 1, 64);
            if (h == 0) vv_[r] = s;
        }
        __syncthreads();
        // P8: g1 = Ginv vv (+v.g1, uw.g1); g2 = Ginv uw (+uw.g2)
        {
            float4 acc = {0,0,0,0};
            #pragma unroll
            for (int jt = 0; jt < 16; ++jt) {
                const float4 x = *(const float4*)&vv_[cb + 4*jt];
                acc.x += Greg[4*jt]*x.x;   acc.y += Greg[4*jt+1]*x.y;
                acc.z += Greg[4*jt+2]*x.z; acc.w += Greg[4*jt+3]*x.w;
            }
            float s1 = (acc.x+acc.y)+(acc.z+acc.w); s1 += __shfl_xor(s1, 1, 64);
            if (h == 0) vg1[r] = s1;
            float pa = (h == 0) ? s1*vv_[r] : 0.f; DOT_ACC(pa, 0);
            float pb = (h == 0) ? s1*vuw[r] : 0.f; DOT_ACC(pb, 1);
            float4 a2 = {0,0,0,0};
            #pragma unroll
            for (int jt = 0; jt < 16; ++jt) {
                const float4 x = *(const float4*)&vuw[cb + 4*jt];
                a2.x += Greg[4*jt]*x.x;   a2.y += Greg[4*jt+1]*x.y;
                a2.z += Greg[4*jt+2]*x.z; a2.w += Greg[4*jt+3]*x.w;
            }
            float s2 = (a2.x+a2.y)+(a2.z+a2.w); s2 += __shfl_xor(s2, 1, 64);
            if (h == 0) vg2[r] = s2;
            float pc = (h == 0) ? s2*vuw[r] : 0.f; DOT_ACC(pc, 2);
        }
        __syncthreads();
        const float s_vg1  = wred[0]+wred[4]+wred[8]+wred[12];
        const float s_uwg1 = wred[1]+wred[5]+wred[9]+wred[13];
        const float s_uwg2 = wred[2]+wred[6]+wred[10]+wred[14];
        // 2x2 Woodbury capacitance: G_new = G + v c^T + c v^T + d2 c c^T
        // S = [[0,1],[1,d2]], S^-1 = [[-d2,1],[1,0]]; c = uw/sig, gc = g2/sig
        const float b11 = s_vg1 - d2;
        const float b12 = 1.0f + s_uwg1*inv_sig;
        const float b22 = s_uwg2*inv_sig*inv_sig;
        const float idet = 1.0f / (b11*b22 - b12*b12);
        const float K11 = b22*idet, K12v = -b12*idet, K22 = b11*idet;
        const float k12s = K12v*inv_sig;
        const float k22s = K22*inv_sig*inv_sig;
        // P9: A += c dl^T ; U -= c uw^T ; Ginv -= [g1 gc] K [g1 gc]^T ; prefetch z
        {
            const float cr  = vuw[r]*inv_sig;
            const float g1r = vg1[r], g2r = vg2[r];
            const float ar_ = K11*g1r + k12s*g2r;
            const float br_ = k12s*g1r + k22s*g2r;
            #pragma unroll
            for (int jt = 0; jt < 16; ++jt) {
                const float4 dd = *(const float4*)&vdl[cb + 4*jt];
                float4 aa = *(float4*)&A[r*LDA + cb + 4*jt];
                aa.x += cr*dd.x; aa.y += cr*dd.y; aa.z += cr*dd.z; aa.w += cr*dd.w;
                *(float4*)&A[r*LDA + cb + 4*jt] = aa;
                const float4 uu = *(const float4*)&vuw[cb + 4*jt];
                Ureg[4*jt]   -= cr*uu.x; Ureg[4*jt+1] -= cr*uu.y;
                Ureg[4*jt+2] -= cr*uu.z; Ureg[4*jt+3] -= cr*uu.w;
                const float4 q1 = *(const float4*)&vg1[cb + 4*jt];
                const float4 q2 = *(const float4*)&vg2[cb + 4*jt];
                Greg[4*jt]   -= ar_*q1.x + br_*q2.x;
                Greg[4*jt+1] -= ar_*q1.y + br_*q2.y;
                Greg[4*jt+2] -= ar_*q1.z + br_*q2.z;
                Greg[4*jt+3] -= ar_*q1.w + br_*q2.w;
            }
            if (t < 32 && e + 1 < EE) {
                const float4 zz = *(const float4*)&zin[((size_t)(e+1)*BB + b)*CC + 4*t];
                *(float4*)&vz[4*t] = zz;
            }
        }
        __syncthreads();
    }

    // epilogue: post_mean
    {
        float* dst = out + (size_t)b*(MM*CC) + r*CC + cb;
        #pragma unroll
        for (int jt = 0; jt < 16; ++jt)
            *(float4*)&dst[4*jt] = *(const float4*)&A[r*LDA + cb + 4*jt];
    }
    // post_cov + diag extraction (static indexing only)
    float qd = 0.f;
    {
        float* dst = out + (size_t)BB*(MM*CC) + (size_t)b*(MM*MM) + r*MM + cb;
        #pragma unroll
        for (int jt = 0; jt < 16; ++jt) {
            float4 v;
            v.x = Ureg[4*jt]; v.y = Ureg[4*jt+1]; v.z = Ureg[4*jt+2]; v.w = Ureg[4*jt+3];
            *(float4*)&dst[4*jt] = v;
            if (cb + 4*jt     == r) qd = v.x;
            if (cb + 4*jt + 1 == r) qd = v.y;
            if (cb + 4*jt + 2 == r) qd = v.z;
            if (cb + 4*jt + 3 == r) qd = v.w;
        }
    }
    // dkl: C*sum(q/p) + sum((A-A0)^2)/p - C*M + C*sum(log p - log q), mean over B
    {
        const float inv_p = 1.0f / pvar;
        float acc = 0.f;
        const float* src = mean0 + r*CC + cb;
        #pragma unroll
        for (int jt = 0; jt < 16; ++jt) {
            const float4 a0 = *(const float4*)&src[4*jt];
            const float4 af = *(const float4*)&A[r*LDA + cb + 4*jt];
            const float dx = af.x-a0.x, dy = af.y-a0.y, dz = af.z-a0.z, dw = af.w-a0.w;
            acc += dx*dx + dy*dy + dz*dz + dw*dw;
        }
        float local = acc * inv_p;
        if ((r >> 6) == h)   // owner of diagonal element of row r
            local += (float)CC * (qd*inv_p + logf(pvar) - logf(qd));
        #pragma unroll
        for (int m2 = 1; m2 < 64; m2 <<= 1) local += __shfl_xor(local, m2, 64);
        if (lane == 0) wred[wv*4] = local;
        __syncthreads();
        if (t == 0) {
            const float tot = wred[0] + wred[4] + wred[8] + wred[12] - (float)(CC*MM);
            atomicAdd(out + (size_t)2*BB*MM*CC, tot * (1.0f/(float)BB));
        }
    }
}

extern "C" void kernel_launch(void* const* d_in, const int* in_sizes, int n_in,
                              void* d_out, int out_size, void* d_ws, size_t ws_size,
                              hipStream_t stream) {
    (void)in_sizes; (void)n_in; (void)out_size;
    const float* zin   = (const float*)d_in[0];
    const float* mean0 = (const float*)d_in[1];
    const float* lvar  = (const float*)d_in[2];
    float* out = (float*)d_out;
    float* dkl = out + (size_t)2*BB*MM*CC;   // 16,777,216
    const int use_ws = (d_ws != nullptr && ws_size >= (size_t)MM*MM*4) ? 1 : 0;
    float* ginv0 = (float*)d_ws;

    // allow >64KB dynamic LDS (idempotent, host-side, capture-safe)
    hipFuncSetAttribute((const void*)gpm_setup, hipFuncAttributeMaxDynamicSharedMemorySize, SMEM_BYTES);
    hipFuncSetAttribute((const void*)gpm_main,  hipFuncAttributeMaxDynamicSharedMemorySize, SMEM_BYTES);

    hipMemsetAsync(dkl, 0, sizeof(float), stream);
    if (use_ws)
        gpm_setup<<<1, 256, SMEM_BYTES, stream>>>(mean0, ginv0);
    gpm_main<<<BB, 256, SMEM_BYTES, stream>>>(zin, mean0, lvar, out, ginv0, use_ws);
}

// Round 2
// 3871.807 us; speedup vs baseline: 1.4125x; 1.4125x over previous
//
#include <hip/hip_runtime.h>
#include <math.h>

// Problem constants (E,B,M,C) = (64, 512, 128, 128), sigma=0.5, eps=1e-6
#define MM   128
#define CC   128
#define EE   64
#define BB   512
#define LDA  132          // padded row stride for A in LDS
#define SIG2 0.25f
#define EPSV 1e-6f

// dynamic LDS layout (floats)
#define A_OFF      0
#define VS(i)      (128*LDA + (i)*128)       // 11 vector slots of 128
#define PA_OFF     (128*LDA + 11*128)        // partial buffer A (512)
#define PB_OFF     (PA_OFF + 512)            // partial buffer B (512)
#define WR_OFF     (PB_OFF + 512)            // 32 floats scalar slots
#define SMEM_FLOATS (WR_OFF + 32)
#define SMEM_BYTES  (SMEM_FLOATS * 4)        // 77,440 B -> 2 blocks/CU

// ---------------------------------------------------------------------------
// Thread mapping (512 threads): w = t>>6 (wave), l = t&63
//   r = 64*(w&1) + l   (row owned, 0..127)
//   q = w>>1           (column chunk, 0..3), cb = 32*q
// Partial-sum slot for element r from chunk q: pred[4*r + q]
// Combiner for element i: thread t == i (waves 0,1), reads pred[4i..4i+4).
// ---------------------------------------------------------------------------

// Ginv0 = (A A^T + SIG2*I)^-1, A in LDS [128][LDA]; destroys A buffer.
// Result: Gout = row r, cols [cb, cb+32). Caller synced after loading A.
__device__ void compute_ginv512(float* sm, float (&Gout)[32],
                                const int r, const int q, const int cb) {
    float* A   = sm + A_OFF;
    float* piv = sm + WR_OFF + 30;
    float Gacc[32];
    #pragma unroll
    for (int j = 0; j < 32; ++j) Gacc[j] = 0.f;
    // G0 block: row r  x  rows [cb, cb+32)
    #pragma unroll 1
    for (int cc = 0; cc < 8; ++cc) {
        const float4 a0 = *(const float4*)&A[r*LDA + 16*cc + 0];
        const float4 a1 = *(const float4*)&A[r*LDA + 16*cc + 4];
        const float4 a2 = *(const float4*)&A[r*LDA + 16*cc + 8];
        const float4 a3 = *(const float4*)&A[r*LDA + 16*cc + 12];
        #pragma unroll
        for (int jj = 0; jj < 32; ++jj) {
            const float* Br = &A[(cb + jj)*LDA + 16*cc];
            const float4 b0 = *(const float4*)&Br[0];
            const float4 b1 = *(const float4*)&Br[4];
            const float4 b2 = *(const float4*)&Br[8];
            const float4 b3 = *(const float4*)&Br[12];
            Gacc[jj] += a0.x*b0.x + a0.y*b0.y + a0.z*b0.z + a0.w*b0.w
                      + a1.x*b1.x + a1.y*b1.y + a1.z*b1.z + a1.w*b1.w
                      + a2.x*b2.x + a2.y*b2.y + a2.z*b2.z + a2.w*b2.w
                      + a3.x*b3.x + a3.y*b3.y + a3.z*b3.z + a3.w*b3.w;
        }
    }
    #pragma unroll
    for (int jj = 0; jj < 32; ++jj)
        if (cb + jj == r) Gacc[jj] += SIG2;
    __syncthreads();                          // all G0 reads of A done
    #pragma unroll
    for (int j = 0; j < 8; ++j) {
        float4 v; v.x = Gacc[4*j]; v.y = Gacc[4*j+1]; v.z = Gacc[4*j+2]; v.w = Gacc[4*j+3];
        *(float4*)&A[r*LDA + cb + 4*j] = v;
    }
    // in-place Gauss-Jordan (SPD, no pivoting); 4 phases per k (cross-wave safe)
    #pragma unroll 1
    for (int k = 0; k < 128; ++k) {
        const int kq = k >> 5;
        __syncthreads();
        if (r == k && q == kq) piv[0] = 1.0f / A[k*LDA + k];
        __syncthreads();
        if (r == k) {
            const float pinv = piv[0];
            #pragma unroll
            for (int j = 0; j < 8; ++j) {
                float4 g = *(float4*)&A[k*LDA + cb + 4*j];
                g.x *= pinv; g.y *= pinv; g.z *= pinv; g.w *= pinv;
                *(float4*)&A[k*LDA + cb + 4*j] = g;
            }
            if (q == kq) A[k*LDA + k] = pinv;  // identity-column trick
        }
        __syncthreads();
        const float f = (r == k) ? 0.f : A[r*LDA + k];
        __syncthreads();
        if (r != k) {
            #pragma unroll
            for (int j = 0; j < 8; ++j) {
                float4 own = *(float4*)&A[r*LDA + cb + 4*j];
                const float4 pv = *(const float4*)&A[k*LDA + cb + 4*j];
                own.x -= f*pv.x; own.y -= f*pv.y; own.z -= f*pv.z; own.w -= f*pv.w;
                *(float4*)&A[r*LDA + cb + 4*j] = own;
            }
            if (q == kq) A[r*LDA + k] -= f;    // blind gave f - f*pinv; want -f*pinv
        }
    }
    __syncthreads();
    #pragma unroll
    for (int j = 0; j < 8; ++j) {
        const float4 v = *(const float4*)&A[r*LDA + cb + 4*j];
        Gout[4*j] = v.x; Gout[4*j+1] = v.y; Gout[4*j+2] = v.z; Gout[4*j+3] = v.w;
    }
    __syncthreads();                          // caller may overwrite A
}

__global__ __launch_bounds__(512, 4) void gpm_setup(const float* __restrict__ mean0,
                                                    float* __restrict__ ginv0) {
    extern __shared__ float sm[];
    const int t = threadIdx.x, w = t >> 6, l = t & 63;
    const int r = ((w & 1) << 6) | l, q = w >> 1, cb = q << 5;
    float* A = sm + A_OFF;
    const float* src = mean0 + r*CC + cb;
    #pragma unroll
    for (int j = 0; j < 8; ++j)
        *(float4*)&A[r*LDA + cb + 4*j] = *(const float4*)&src[4*j];
    __syncthreads();
    float G[32];
    compute_ginv512(sm, G, r, q, cb);
    #pragma unroll
    for (int j = 0; j < 8; ++j) {
        float4 v; v.x = G[4*j]; v.y = G[4*j+1]; v.z = G[4*j+2]; v.w = G[4*j+3];
        *(float4*)&ginv0[r*CC + cb + 4*j] = v;
    }
}

// ---- per-phase helpers (use kernel-local names A, r, q, cb, t, Greg, Ureg) ----
#define ROWMV(XV, PR) { float4 acc_ = {0,0,0,0};                                  \
    const float* Arp_ = &A[r*LDA + cb]; const float* xp_ = &(XV)[cb];             \
    _Pragma("unroll") for (int j_ = 0; j_ < 8; ++j_) {                            \
        const float4 a_ = *(const float4*)&Arp_[4*j_];                            \
        const float4 x_ = *(const float4*)&xp_[4*j_];                             \
        acc_.x += a_.x*x_.x; acc_.y += a_.y*x_.y;                                 \
        acc_.z += a_.z*x_.z; acc_.w += a_.w*x_.w; }                               \
    (PR)[4*r + q] = (acc_.x + acc_.y) + (acc_.z + acc_.w); }

#define GMV(XV, PR) { float4 acc_ = {0,0,0,0}; const float* xp_ = &(XV)[cb];      \
    _Pragma("unroll") for (int j_ = 0; j_ < 8; ++j_) {                            \
        const float4 x_ = *(const float4*)&xp_[4*j_];                             \
        acc_.x += Greg[4*j_]*x_.x;   acc_.y += Greg[4*j_+1]*x_.y;                 \
        acc_.z += Greg[4*j_+2]*x_.z; acc_.w += Greg[4*j_+3]*x_.w; }               \
    (PR)[4*r + q] = (acc_.x + acc_.y) + (acc_.z + acc_.w); }

#define UMV(XV, PR) { float4 acc_ = {0,0,0,0}; const float* xp_ = &(XV)[cb];      \
    _Pragma("unroll") for (int j_ = 0; j_ < 8; ++j_) {                            \
        const float4 x_ = *(const float4*)&xp_[4*j_];                             \
        acc_.x += Ureg[4*j_]*x_.x;   acc_.y += Ureg[4*j_+1]*x_.y;                 \
        acc_.z += Ureg[4*j_+2]*x_.z; acc_.w += Ureg[4*j_+3]*x_.w; }               \
    (PR)[4*r + q] = (acc_.x + acc_.y) + (acc_.z + acc_.w); }

#define COLMV(YV, PR) { float acc_ = 0.f;                                         \
    _Pragma("unroll") for (int m_ = 0; m_ < 32; ++m_)                             \
        acc_ += (YV)[cb + m_] * A[(cb + m_)*LDA + r];                             \
    (PR)[4*r + q] = acc_; }

#define COMB4(PR) ({ const float4 p_ = *(const float4*)&(PR)[4*t];                \
                     (p_.x + p_.y) + (p_.z + p_.w); })

#define WRED(val, slot) { float v_ = (val);                                       \
    v_ += __shfl_xor(v_, 1, 64);  v_ += __shfl_xor(v_, 2, 64);                    \
    v_ += __shfl_xor(v_, 4, 64);  v_ += __shfl_xor(v_, 8, 64);                    \
    v_ += __shfl_xor(v_, 16, 64); v_ += __shfl_xor(v_, 32, 64);                   \
    if (l == 0) wred[w*8 + (slot)] = v_; }

// ---------------------------------------------------------------------------
// Main: one block (512 thr) per batch element, 64 sequential Kalman steps.
// A (mean) in LDS; U (cov) and Ginv chunks in registers (32 floats each).
// ---------------------------------------------------------------------------
__global__ __launch_bounds__(512, 4) void gpm_main(
        const float* __restrict__ zin, const float* __restrict__ mean0,
        const float* __restrict__ lvar, float* __restrict__ out,
        const float* __restrict__ ginv0, const int use_ws) {
    extern __shared__ float sm[];
    float* A    = sm + A_OFF;
    float* vz   = sm + VS(0);
    float* vaz  = sm + VS(1);
    float* vw0  = sm + VS(2);
    float* vt0  = sm + VS(3);
    float* vrr  = sm + VS(4);
    float* vw   = sm + VS(5);
    float* vdl  = sm + VS(6);
    float* vvv  = sm + VS(7);
    float* vuw  = sm + VS(8);
    float* vg1  = sm + VS(9);
    float* vg2  = sm + VS(10);
    float* pra  = sm + PA_OFF;
    float* prb  = sm + PB_OFF;
    float* wred = sm + WR_OFF;

    const int t = threadIdx.x, b = blockIdx.x;
    const int w = t >> 6, l = t & 63;
    const int r = ((w & 1) << 6) | l, q = w >> 1, cb = q << 5;

    // prologue: A0 -> LDS
    {
        const float* src = mean0 + r*CC + cb;
        #pragma unroll
        for (int j = 0; j < 8; ++j)
            *(float4*)&A[r*LDA + cb + 4*j] = *(const float4*)&src[4*j];
    }
    const float pvar = expf(lvar[0]) + EPSV;
    float Ureg[32], Greg[32];
    #pragma unroll
    for (int j = 0; j < 32; ++j) Ureg[j] = (cb + j == r) ? pvar : 0.f;

    if (use_ws) {
        const float* src = ginv0 + r*CC + cb;
        #pragma unroll
        for (int j = 0; j < 8; ++j) {
            const float4 v = *(const float4*)&src[4*j];
            Greg[4*j] = v.x; Greg[4*j+1] = v.y; Greg[4*j+2] = v.z; Greg[4*j+3] = v.w;
        }
    } else {
        __syncthreads();
        compute_ginv512(sm, Greg, r, q, cb);   // destroys A, internal syncs
        const float* src = mean0 + r*CC + cb;  // reload A0
        #pragma unroll
        for (int j = 0; j < 8; ++j)
            *(float4*)&A[r*LDA + cb + 4*j] = *(const float4*)&src[4*j];
    }
    if (t < 32)
        *(float4*)&vz[4*t] = *(const float4*)&zin[(size_t)b*CC + 4*t];
    __syncthreads();

    float az_r = 0, w0_r = 0, w_r = 0, dl_r = 0, uw_r = 0, vv_r = 0, g2_r = 0;
    float d2 = 0, sig = 0, inv_sig = 0;

    #pragma unroll 1
    for (int e = 0; e < EE; ++e) {
        ROWMV(vz, pra);                                   // P1: az = A z
        __syncthreads();
        if (t < 128) { az_r = COMB4(pra); vaz[t] = az_r; }
        __syncthreads();
        GMV(vaz, pra);                                    // P2: w0 = Ginv az
        __syncthreads();
        if (t < 128) { w0_r = COMB4(pra); vw0[t] = w0_r; }
        __syncthreads();
        COLMV(vw0, pra);                                  // P3: t0 = A^T w0
        __syncthreads();
        if (t < 128) { vt0[t] = COMB4(pra); }
        __syncthreads();
        ROWMV(vt0, pra);                                  // P4: rr = az - A t0 - s2 w0
        __syncthreads();
        if (t < 128) { vrr[t] = az_r - COMB4(pra) - SIG2*w0_r; }
        __syncthreads();
        GMV(vrr, pra);                                    // P5: w = w0 + Ginv rr
        __syncthreads();
        if (t < 128) { w_r = w0_r + COMB4(pra); vw[t] = w_r; }
        __syncthreads();
        COLMV(vw, pra);                                   // P6: t2 = A^T w ; uw = U w
        UMV(vw, prb);
        __syncthreads();
        if (t < 128) {
            dl_r = vz[t] - COMB4(pra); vdl[t] = dl_r;
            uw_r = COMB4(prb);         vuw[t] = uw_r;
            WRED(dl_r*dl_r, 0);
            WRED(uw_r*w_r, 1);
        }
        __syncthreads();
        d2 = wred[0] + wred[8];
        sig = wred[1] + wred[9] + SIG2;
        inv_sig = 1.0f / sig;
        ROWMV(vdl, pra);                                  // P7: vv = A dl ; g2 = Ginv uw
        GMV(vuw, prb);
        __syncthreads();
        if (t < 128) {
            vv_r = COMB4(pra); vvv[t] = vv_r;
            g2_r = COMB4(prb); vg2[t] = g2_r;
            WRED(uw_r*g2_r, 2);
        }
        __syncthreads();
        GMV(vvv, pra);                                    // P8: g1 = Ginv vv
        __syncthreads();
        if (t < 128) {
            const float g1_r = COMB4(pra); vg1[t] = g1_r;
            WRED(g1_r*vv_r, 3);
            WRED(g1_r*uw_r, 4);
        }
        __syncthreads();
        {   // P9: rank-1/2 updates of A, U, Ginv (2x2 Woodbury capacitance)
            const float s_uwg2 = wred[2] + wred[10];
            const float s_vg1  = wred[3] + wred[11];
            const float s_uwg1 = wred[4] + wred[12];
            const float b11 = s_vg1 - d2;
            const float b12 = 1.0f + s_uwg1*inv_sig;
            const float b22 = s_uwg2*inv_sig*inv_sig;
            const float idet = 1.0f / (b11*b22 - b12*b12);
            const float K11 = b22*idet, K12v = -b12*idet, K22 = b11*idet;
            const float k12s = K12v*inv_sig;
            const float k22s = K22*inv_sig*inv_sig;
            const float cr  = vuw[r]*inv_sig;
            const float g1r = vg1[r], g2r = vg2[r];
            const float ar_ = K11*g1r + k12s*g2r;
            const float br_ = k12s*g1r + k22s*g2r;
            float* Arow = &A[r*LDA + cb];
            #pragma unroll
            for (int j = 0; j < 8; ++j) {
                const float4 dd = *(const float4*)&vdl[cb + 4*j];
                float4 aa = *(float4*)&Arow[4*j];
                aa.x += cr*dd.x; aa.y += cr*dd.y; aa.z += cr*dd.z; aa.w += cr*dd.w;
                *(float4*)&Arow[4*j] = aa;
                const float4 uu = *(const float4*)&vuw[cb + 4*j];
                Ureg[4*j]   -= cr*uu.x; Ureg[4*j+1] -= cr*uu.y;
                Ureg[4*j+2] -= cr*uu.z; Ureg[4*j+3] -= cr*uu.w;
                const float4 q1 = *(const float4*)&vg1[cb + 4*j];
                const float4 q2 = *(const float4*)&vg2[cb + 4*j];
                Greg[4*j]   -= ar_*q1.x + br_*q2.x;
                Greg[4*j+1] -= ar_*q1.y + br_*q2.y;
                Greg[4*j+2] -= ar_*q1.z + br_*q2.z;
                Greg[4*j+3] -= ar_*q1.w + br_*q2.w;
            }
            if (t < 32 && e + 1 < EE)
                *(float4*)&vz[4*t] = *(const float4*)&zin[((size_t)(e+1)*BB + b)*CC + 4*t];
        }
        __syncthreads();
    }

    // epilogue: post_mean
    {
        float* dst = out + (size_t)b*(MM*CC) + r*CC + cb;
        const float* srcA = &A[r*LDA + cb];
        #pragma unroll
        for (int j = 0; j < 8; ++j)
            *(float4*)&dst[4*j] = *(const float4*)&srcA[4*j];
    }
    // post_cov + diag extraction (static indexing only)
    float qd = 1.f;
    {
        float* dst = out + (size_t)BB*(MM*CC) + (size_t)b*(MM*MM) + r*MM + cb;
        #pragma unroll
        for (int j = 0; j < 8; ++j) {
            float4 v;
            v.x = Ureg[4*j]; v.y = Ureg[4*j+1]; v.z = Ureg[4*j+2]; v.w = Ureg[4*j+3];
            *(float4*)&dst[4*j] = v;
            if (cb + 4*j     == r) qd = v.x;
            if (cb + 4*j + 1 == r) qd = v.y;
            if (cb + 4*j + 2 == r) qd = v.z;
            if (cb + 4*j + 3 == r) qd = v.w;
        }
    }
    // dkl = mean_b[ C*sum(q/p) + sum((A-A0)^2)/p - C*M + C*sum(log p - log q) ]
    {
        const float inv_p = 1.0f / pvar;
        float acc = 0.f;
        const float* src  = mean0 + r*CC + cb;
        const float* srcA = &A[r*LDA + cb];
        #pragma unroll
        for (int j = 0; j < 8; ++j) {
            const float4 a0 = *(const float4*)&src[4*j];
            const float4 af = *(const float4*)&srcA[4*j];
            const float dx = af.x-a0.x, dy = af.y-a0.y, dz = af.z-a0.z, dw = af.w-a0.w;
            acc += dx*dx + dy*dy + dz*dz + dw*dw;
        }
        float local = acc * inv_p;
        if (q == (r >> 5))   // owner of diagonal element of row r
            local += (float)CC * (qd*inv_p + logf(pvar) - logf(qd));
        #pragma unroll
        for (int m2 = 1; m2 < 64; m2 <<= 1) local += __shfl_xor(local, m2, 64);
        if (l == 0) wred[16 + w] = local;
        __syncthreads();
        if (t == 0) {
            float tot = 0.f;
            #pragma unroll
            for (int i = 0; i < 8; ++i) tot += wred[16 + i];
            tot -= (float)(CC*MM);
            atomicAdd(out + (size_t)2*BB*MM*CC, tot * (1.0f/(float)BB));
        }
    }
}

extern "C" void kernel_launch(void* const* d_in, const int* in_sizes, int n_in,
                              void* d_out, int out_size, void* d_ws, size_t ws_size,
                              hipStream_t stream) {
    (void)in_sizes; (void)n_in; (void)out_size;
    const float* zin   = (const float*)d_in[0];
    const float* mean0 = (const float*)d_in[1];
    const float* lvar  = (const float*)d_in[2];
    float* out = (float*)d_out;
    float* dkl = out + (size_t)2*BB*MM*CC;
    const int use_ws = (d_ws != nullptr && ws_size >= (size_t)MM*MM*4) ? 1 : 0;
    float* ginv0 = (float*)d_ws;

    hipFuncSetAttribute((const void*)gpm_setup, hipFuncAttributeMaxDynamicSharedMemorySize, SMEM_BYTES);
    hipFuncSetAttribute((const void*)gpm_main,  hipFuncAttributeMaxDynamicSharedMemorySize, SMEM_BYTES);

    hipMemsetAsync(dkl, 0, sizeof(float), stream);
    if (use_ws)
        gpm_setup<<<1, 512, SMEM_BYTES, stream>>>(mean0, ginv0);
    gpm_main<<<BB, 512, SMEM_BYTES, stream>>>(zin, mean0, lvar, out, ginv0, use_ws);
}

// Round 3
// 3643.874 us; speedup vs baseline: 1.5009x; 1.0626x over previous
//
#include <hip/hip_runtime.h>
#include <math.h>

// Problem constants (E,B,M,C) = (64, 512, 128, 128), sigma=0.5, eps=1e-6
#define MM   128
#define CC   128
#define EE   64
#define BB   512
#define LDA  132          // padded row stride for A in LDS
#define SIG2 0.25f
#define EPSV 1e-6f

// dynamic LDS layout (floats)
#define A_OFF      0
#define VS(i)      (128*LDA + (i)*128)       // 11 vector slots of 128
#define PA_OFF     (128*LDA + 11*128)        // partial buffer A (512)
#define PB_OFF     (PA_OFF + 512)            // partial buffer B (512)
#define WR_OFF     (PB_OFF + 512)            // 32 floats scalar slots
#define SMEM_FLOATS (WR_OFF + 32)
#define SMEM_BYTES  (SMEM_FLOATS * 4)        // 77,440 B -> 2 blocks/CU

// ---------------------------------------------------------------------------
// Thread mapping (512 threads): w = t>>6 (wave), l = t&63
//   r = 64*(w&1) + l   (row owned, 0..127)
//   q = w>>1           (column chunk, 0..3), cb = 32*q
// Partial-sum slot for element r from chunk q: pred[4*r + q]
// Combiner for element i: thread t == i (waves 0,1), reads pred[4i..4i+4).
// NOTE: __launch_bounds__ has NO second arg on purpose — the waves-per-eu
// minimum makes the backend spill state arrays to scratch (rounds 1&2:
// 10-13 GB of HBM scratch traffic). One 8-wave block only requires
// 2 waves/SIMD -> VGPR budget 256, plenty for the ~100 live registers.
// ---------------------------------------------------------------------------

// Ginv0 = (A A^T + SIG2*I)^-1, A in LDS [128][LDA]; destroys A buffer.
// Result: Gout = row r, cols [cb, cb+32). Caller synced after loading A.
__device__ void compute_ginv512(float* sm, float (&Gout)[32],
                                const int r, const int q, const int cb) {
    float* A   = sm + A_OFF;
    float* piv = sm + WR_OFF + 30;
    float Gacc[32];
    #pragma unroll
    for (int j = 0; j < 32; ++j) Gacc[j] = 0.f;
    // G0 block: row r  x  rows [cb, cb+32)
    #pragma unroll 1
    for (int cc = 0; cc < 8; ++cc) {
        const float4 a0 = *(const float4*)&A[r*LDA + 16*cc + 0];
        const float4 a1 = *(const float4*)&A[r*LDA + 16*cc + 4];
        const float4 a2 = *(const float4*)&A[r*LDA + 16*cc + 8];
        const float4 a3 = *(const float4*)&A[r*LDA + 16*cc + 12];
        #pragma unroll
        for (int jj = 0; jj < 32; ++jj) {
            const float* Br = &A[(cb + jj)*LDA + 16*cc];
            const float4 b0 = *(const float4*)&Br[0];
            const float4 b1 = *(const float4*)&Br[4];
            const float4 b2 = *(const float4*)&Br[8];
            const float4 b3 = *(const float4*)&Br[12];
            Gacc[jj] += a0.x*b0.x + a0.y*b0.y + a0.z*b0.z + a0.w*b0.w
                      + a1.x*b1.x + a1.y*b1.y + a1.z*b1.z + a1.w*b1.w
                      + a2.x*b2.x + a2.y*b2.y + a2.z*b2.z + a2.w*b2.w
                      + a3.x*b3.x + a3.y*b3.y + a3.z*b3.z + a3.w*b3.w;
        }
    }
    #pragma unroll
    for (int jj = 0; jj < 32; ++jj)
        if (cb + jj == r) Gacc[jj] += SIG2;
    __syncthreads();                          // all G0 reads of A done
    #pragma unroll
    for (int j = 0; j < 8; ++j) {
        float4 v; v.x = Gacc[4*j]; v.y = Gacc[4*j+1]; v.z = Gacc[4*j+2]; v.w = Gacc[4*j+3];
        *(float4*)&A[r*LDA + cb + 4*j] = v;
    }
    // in-place Gauss-Jordan (SPD, no pivoting); 4 phases per k (cross-wave safe)
    #pragma unroll 1
    for (int k = 0; k < 128; ++k) {
        const int kq = k >> 5;
        __syncthreads();
        if (r == k && q == kq) piv[0] = 1.0f / A[k*LDA + k];
        __syncthreads();
        if (r == k) {
            const float pinv = piv[0];
            #pragma unroll
            for (int j = 0; j < 8; ++j) {
                float4 g = *(float4*)&A[k*LDA + cb + 4*j];
                g.x *= pinv; g.y *= pinv; g.z *= pinv; g.w *= pinv;
                *(float4*)&A[k*LDA + cb + 4*j] = g;
            }
            if (q == kq) A[k*LDA + k] = pinv;  // identity-column trick
        }
        __syncthreads();
        const float f = (r == k) ? 0.f : A[r*LDA + k];
        __syncthreads();
        if (r != k) {
            #pragma unroll
            for (int j = 0; j < 8; ++j) {
                float4 own = *(float4*)&A[r*LDA + cb + 4*j];
                const float4 pv = *(const float4*)&A[k*LDA + cb + 4*j];
                own.x -= f*pv.x; own.y -= f*pv.y; own.z -= f*pv.z; own.w -= f*pv.w;
                *(float4*)&A[r*LDA + cb + 4*j] = own;
            }
            if (q == kq) A[r*LDA + k] -= f;    // blind gave f - f*pinv; want -f*pinv
        }
    }
    __syncthreads();
    #pragma unroll
    for (int j = 0; j < 8; ++j) {
        const float4 v = *(const float4*)&A[r*LDA + cb + 4*j];
        Gout[4*j] = v.x; Gout[4*j+1] = v.y; Gout[4*j+2] = v.z; Gout[4*j+3] = v.w;
    }
    __syncthreads();                          // caller may overwrite A
}

__global__ __launch_bounds__(512) void gpm_setup(const float* __restrict__ mean0,
                                                 float* __restrict__ ginv0) {
    extern __shared__ float sm[];
    const int t = threadIdx.x, w = t >> 6, l = t & 63;
    const int r = ((w & 1) << 6) | l, q = w >> 1, cb = q << 5;
    float* A = sm + A_OFF;
    const float* src = mean0 + r*CC + cb;
    #pragma unroll
    for (int j = 0; j < 8; ++j)
        *(float4*)&A[r*LDA + cb + 4*j] = *(const float4*)&src[4*j];
    __syncthreads();
    float G[32];
    compute_ginv512(sm, G, r, q, cb);
    #pragma unroll
    for (int j = 0; j < 8; ++j) {
        float4 v; v.x = G[4*j]; v.y = G[4*j+1]; v.z = G[4*j+2]; v.w = G[4*j+3];
        *(float4*)&ginv0[r*CC + cb + 4*j] = v;
    }
}

// ---- per-phase helpers (use kernel-local names A, r, q, cb, t, Greg, Ureg) ----
#define ROWMV(XV, PR) { float4 acc_ = {0,0,0,0};                                  \
    const float* Arp_ = &A[r*LDA + cb]; const float* xp_ = &(XV)[cb];             \
    _Pragma("unroll") for (int j_ = 0; j_ < 8; ++j_) {                            \
        const float4 a_ = *(const float4*)&Arp_[4*j_];                            \
        const float4 x_ = *(const float4*)&xp_[4*j_];                             \
        acc_.x += a_.x*x_.x; acc_.y += a_.y*x_.y;                                 \
        acc_.z += a_.z*x_.z; acc_.w += a_.w*x_.w; }                               \
    (PR)[4*r + q] = (acc_.x + acc_.y) + (acc_.z + acc_.w); }

#define GMV(XV, PR) { float4 acc_ = {0,0,0,0}; const float* xp_ = &(XV)[cb];      \
    _Pragma("unroll") for (int j_ = 0; j_ < 8; ++j_) {                            \
        const float4 x_ = *(const float4*)&xp_[4*j_];                             \
        acc_.x += Greg[4*j_]*x_.x;   acc_.y += Greg[4*j_+1]*x_.y;                 \
        acc_.z += Greg[4*j_+2]*x_.z; acc_.w += Greg[4*j_+3]*x_.w; }               \
    (PR)[4*r + q] = (acc_.x + acc_.y) + (acc_.z + acc_.w); }

#define UMV(XV, PR) { float4 acc_ = {0,0,0,0}; const float* xp_ = &(XV)[cb];      \
    _Pragma("unroll") for (int j_ = 0; j_ < 8; ++j_) {                            \
        const float4 x_ = *(const float4*)&xp_[4*j_];                             \
        acc_.x += Ureg[4*j_]*x_.x;   acc_.y += Ureg[4*j_+1]*x_.y;                 \
        acc_.z += Ureg[4*j_+2]*x_.z; acc_.w += Ureg[4*j_+3]*x_.w; }               \
    (PR)[4*r + q] = (acc_.x + acc_.y) + (acc_.z + acc_.w); }

#define COLMV(YV, PR) { float acc_ = 0.f;                                         \
    _Pragma("unroll") for (int m_ = 0; m_ < 32; ++m_)                             \
        acc_ += (YV)[cb + m_] * A[(cb + m_)*LDA + r];                             \
    (PR)[4*r + q] = acc_; }

#define COMB4(PR) ({ const float4 p_ = *(const float4*)&(PR)[4*t];                \
                     (p_.x + p_.y) + (p_.z + p_.w); })

#define WRED(val, slot) { float v_ = (val);                                       \
    v_ += __shfl_xor(v_, 1, 64);  v_ += __shfl_xor(v_, 2, 64);                    \
    v_ += __shfl_xor(v_, 4, 64);  v_ += __shfl_xor(v_, 8, 64);                    \
    v_ += __shfl_xor(v_, 16, 64); v_ += __shfl_xor(v_, 32, 64);                   \
    if (l == 0) wred[w*8 + (slot)] = v_; }

// ---------------------------------------------------------------------------
// Main: one block (512 thr) per batch element, 64 sequential Kalman steps.
// A (mean) in LDS; U (cov) and Ginv chunks in registers (32 floats each).
// ---------------------------------------------------------------------------
__global__ __launch_bounds__(512) void gpm_main(
        const float* __restrict__ zin, const float* __restrict__ mean0,
        const float* __restrict__ lvar, float* __restrict__ out,
        const float* __restrict__ ginv0, const int use_ws) {
    extern __shared__ float sm[];
    float* A    = sm + A_OFF;
    float* vz   = sm + VS(0);
    float* vaz  = sm + VS(1);
    float* vw0  = sm + VS(2);
    float* vt0  = sm + VS(3);
    float* vrr  = sm + VS(4);
    float* vw   = sm + VS(5);
    float* vdl  = sm + VS(6);
    float* vvv  = sm + VS(7);
    float* vuw  = sm + VS(8);
    float* vg1  = sm + VS(9);
    float* vg2  = sm + VS(10);
    float* pra  = sm + PA_OFF;
    float* prb  = sm + PB_OFF;
    float* wred = sm + WR_OFF;

    const int t = threadIdx.x, b = blockIdx.x;
    const int w = t >> 6, l = t & 63;
    const int r = ((w & 1) << 6) | l, q = w >> 1, cb = q << 5;

    // prologue: A0 -> LDS
    {
        const float* src = mean0 + r*CC + cb;
        #pragma unroll
        for (int j = 0; j < 8; ++j)
            *(float4*)&A[r*LDA + cb + 4*j] = *(const float4*)&src[4*j];
    }
    const float pvar = expf(lvar[0]) + EPSV;
    float Ureg[32], Greg[32];
    #pragma unroll
    for (int j = 0; j < 32; ++j) Ureg[j] = (cb + j == r) ? pvar : 0.f;

    if (use_ws) {
        const float* src = ginv0 + r*CC + cb;
        #pragma unroll
        for (int j = 0; j < 8; ++j) {
            const float4 v = *(const float4*)&src[4*j];
            Greg[4*j] = v.x; Greg[4*j+1] = v.y; Greg[4*j+2] = v.z; Greg[4*j+3] = v.w;
        }
    } else {
        __syncthreads();
        compute_ginv512(sm, Greg, r, q, cb);   // destroys A, internal syncs
        const float* src = mean0 + r*CC + cb;  // reload A0
        #pragma unroll
        for (int j = 0; j < 8; ++j)
            *(float4*)&A[r*LDA + cb + 4*j] = *(const float4*)&src[4*j];
    }
    if (t < 32)
        *(float4*)&vz[4*t] = *(const float4*)&zin[(size_t)b*CC + 4*t];
    __syncthreads();

    float az_r = 0, w0_r = 0, w_r = 0, dl_r = 0, uw_r = 0, vv_r = 0, g2_r = 0;
    float d2 = 0, sig = 0, inv_sig = 0;

    #pragma unroll 1
    for (int e = 0; e < EE; ++e) {
        ROWMV(vz, pra);                                   // P1: az = A z
        __syncthreads();
        if (t < 128) { az_r = COMB4(pra); vaz[t] = az_r; }
        __syncthreads();
        GMV(vaz, pra);                                    // P2: w0 = Ginv az
        __syncthreads();
        if (t < 128) { w0_r = COMB4(pra); vw0[t] = w0_r; }
        __syncthreads();
        COLMV(vw0, pra);                                  // P3: t0 = A^T w0
        __syncthreads();
        if (t < 128) { vt0[t] = COMB4(pra); }
        __syncthreads();
        ROWMV(vt0, pra);                                  // P4: rr = az - A t0 - s2 w0
        __syncthreads();
        if (t < 128) { vrr[t] = az_r - COMB4(pra) - SIG2*w0_r; }
        __syncthreads();
        GMV(vrr, pra);                                    // P5: w = w0 + Ginv rr
        __syncthreads();
        if (t < 128) { w_r = w0_r + COMB4(pra); vw[t] = w_r; }
        __syncthreads();
        COLMV(vw, pra);                                   // P6: t2 = A^T w ; uw = U w
        UMV(vw, prb);
        __syncthreads();
        if (t < 128) {
            dl_r = vz[t] - COMB4(pra); vdl[t] = dl_r;
            uw_r = COMB4(prb);         vuw[t] = uw_r;
            WRED(dl_r*dl_r, 0);
            WRED(uw_r*w_r, 1);
        }
        __syncthreads();
        d2 = wred[0] + wred[8];
        sig = wred[1] + wred[9] + SIG2;
        inv_sig = 1.0f / sig;
        ROWMV(vdl, pra);                                  // P7: vv = A dl ; g2 = Ginv uw
        GMV(vuw, prb);
        __syncthreads();
        if (t < 128) {
            vv_r = COMB4(pra); vvv[t] = vv_r;
            g2_r = COMB4(prb); vg2[t] = g2_r;
            WRED(uw_r*g2_r, 2);
        }
        __syncthreads();
        GMV(vvv, pra);                                    // P8: g1 = Ginv vv
        __syncthreads();
        if (t < 128) {
            const float g1_r = COMB4(pra); vg1[t] = g1_r;
            WRED(g1_r*vv_r, 3);
            WRED(g1_r*uw_r, 4);
        }
        __syncthreads();
        {   // P9: rank-1/2 updates of A, U, Ginv (2x2 Woodbury capacitance)
            const float s_uwg2 = wred[2] + wred[10];
            const float s_vg1  = wred[3] + wred[11];
            const float s_uwg1 = wred[4] + wred[12];
            const float b11 = s_vg1 - d2;
            const float b12 = 1.0f + s_uwg1*inv_sig;
            const float b22 = s_uwg2*inv_sig*inv_sig;
            const float idet = 1.0f / (b11*b22 - b12*b12);
            const float K11 = b22*idet, K12v = -b12*idet, K22 = b11*idet;
            const float k12s = K12v*inv_sig;
            const float k22s = K22*inv_sig*inv_sig;
            const float cr  = vuw[r]*inv_sig;
            const float g1r = vg1[r], g2r = vg2[r];
            const float ar_ = K11*g1r + k12s*g2r;
            const float br_ = k12s*g1r + k22s*g2r;
            float* Arow = &A[r*LDA + cb];
            #pragma unroll
            for (int j = 0; j < 8; ++j) {
                const float4 dd = *(const float4*)&vdl[cb + 4*j];
                float4 aa = *(float4*)&Arow[4*j];
                aa.x += cr*dd.x; aa.y += cr*dd.y; aa.z += cr*dd.z; aa.w += cr*dd.w;
                *(float4*)&Arow[4*j] = aa;
                const float4 uu = *(const float4*)&vuw[cb + 4*j];
                Ureg[4*j]   -= cr*uu.x; Ureg[4*j+1] -= cr*uu.y;
                Ureg[4*j+2] -= cr*uu.z; Ureg[4*j+3] -= cr*uu.w;
                const float4 q1 = *(const float4*)&vg1[cb + 4*j];
                const float4 q2 = *(const float4*)&vg2[cb + 4*j];
                Greg[4*j]   -= ar_*q1.x + br_*q2.x;
                Greg[4*j+1] -= ar_*q1.y + br_*q2.y;
                Greg[4*j+2] -= ar_*q1.z + br_*q2.z;
                Greg[4*j+3] -= ar_*q1.w + br_*q2.w;
            }
            if (t < 32 && e + 1 < EE)
                *(float4*)&vz[4*t] = *(const float4*)&zin[((size_t)(e+1)*BB + b)*CC + 4*t];
        }
        __syncthreads();
    }

    // epilogue: post_mean
    {
        float* dst = out + (size_t)b*(MM*CC) + r*CC + cb;
        const float* srcA = &A[r*LDA + cb];
        #pragma unroll
        for (int j = 0; j < 8; ++j)
            *(float4*)&dst[4*j] = *(const float4*)&srcA[4*j];
    }
    // post_cov + diag extraction (static indexing only)
    float qd = 1.f;
    {
        float* dst = out + (size_t)BB*(MM*CC) + (size_t)b*(MM*MM) + r*MM + cb;
        #pragma unroll
        for (int j = 0; j < 8; ++j) {
            float4 v;
            v.x = Ureg[4*j]; v.y = Ureg[4*j+1]; v.z = Ureg[4*j+2]; v.w = Ureg[4*j+3];
            *(float4*)&dst[4*j] = v;
            if (cb + 4*j     == r) qd = v.x;
            if (cb + 4*j + 1 == r) qd = v.y;
            if (cb + 4*j + 2 == r) qd = v.z;
            if (cb + 4*j + 3 == r) qd = v.w;
        }
    }
    // dkl = mean_b[ C*sum(q/p) + sum((A-A0)^2)/p - C*M + C*sum(log p - log q) ]
    {
        const float inv_p = 1.0f / pvar;
        float acc = 0.f;
        const float* src  = mean0 + r*CC + cb;
        const float* srcA = &A[r*LDA + cb];
        #pragma unroll
        for (int j = 0; j < 8; ++j) {
            const float4 a0 = *(const float4*)&src[4*j];
            const float4 af = *(const float4*)&srcA[4*j];
            const float dx = af.x-a0.x, dy = af.y-a0.y, dz = af.z-a0.z, dw = af.w-a0.w;
            acc += dx*dx + dy*dy + dz*dz + dw*dw;
        }
        float local = acc * inv_p;
        if (q == (r >> 5))   // owner of diagonal element of row r
            local += (float)CC * (qd*inv_p + logf(pvar) - logf(qd));
        #pragma unroll
        for (int m2 = 1; m2 < 64; m2 <<= 1) local += __shfl_xor(local, m2, 64);
        if (l == 0) wred[16 + w] = local;
        __syncthreads();
        if (t == 0) {
            float tot = 0.f;
            #pragma unroll
            for (int i = 0; i < 8; ++i) tot += wred[16 + i];
            tot -= (float)(CC*MM);
            atomicAdd(out + (size_t)2*BB*MM*CC, tot * (1.0f/(float)BB));
        }
    }
}

extern "C" void kernel_launch(void* const* d_in, const int* in_sizes, int n_in,
                              void* d_out, int out_size, void* d_ws, size_t ws_size,
                              hipStream_t stream) {
    (void)in_sizes; (void)n_in; (void)out_size;
    const float* zin   = (const float*)d_in[0];
    const float* mean0 = (const float*)d_in[1];
    const float* lvar  = (const float*)d_in[2];
    float* out = (float*)d_out;
    float* dkl = out + (size_t)2*BB*MM*CC;
    const int use_ws = (d_ws != nullptr && ws_size >= (size_t)MM*MM*4) ? 1 : 0;
    float* ginv0 = (float*)d_ws;

    hipFuncSetAttribute((const void*)gpm_setup, hipFuncAttributeMaxDynamicSharedMemorySize, SMEM_BYTES);
    hipFuncSetAttribute((const void*)gpm_main,  hipFuncAttributeMaxDynamicSharedMemorySize, SMEM_BYTES);

    hipMemsetAsync(dkl, 0, sizeof(float), stream);
    if (use_ws)
        gpm_setup<<<1, 512, SMEM_BYTES, stream>>>(mean0, ginv0);
    gpm_main<<<BB, 512, SMEM_BYTES, stream>>>(zin, mean0, lvar, out, ginv0, use_ws);
}